// Round 2
// baseline (288.410 us; speedup 1.0000x reference)
//
#include <hip/hip_runtime.h>
#include <hip/hip_bf16.h>

// ---------------------------------------------------------------------------
// ramsey_NN: node MLP (3 layers, train-mode BN) + all-pairs edge head.
// N=2048, F=64, H=128, C=2.  E = N(N-1)/2 = 2096128.
//
// R10 = R9 resubmit (R9 bench died on container-acquire infra, no profile).
// R9 vs R8 (R8 counters: edge_p1 MfmaUtil 19.9 / VALUBusy 51.6 / Occ 35.7,
// per-SIMD demand only ~6% matrix + ~14% VALU -> latency-bound on T prefetch):
//   * edge_p1/p2: T-slice prefetch moved from register double-buffer to
//     per-wave async LDS staging (global_load_lds width=16), barrier-free,
//     counted s_waitcnt vmcnt(4) so next-iter loads stay in flight across
//     the body. Frees 32 VGPRs/wave (ta/tb gone).
//   * R10 hardening: sched_barrier(0) after each inline-asm waitcnt
//     (methodology rule #18 — pin the dependent ds_read/MFMA cluster).
//   * edge_p2: sP overlays the staging LDS after the loop (40 KB total,
//     4 blocks/CU).
//   * k_l3 + k_bi fused (k_bi block b reads only the 8 hb rows that
//     k_l3 block b produces) — one fewer launch.
// ---------------------------------------------------------------------------

typedef short short8 __attribute__((ext_vector_type(8)));   // 8 x bf16
typedef float floatx4 __attribute__((ext_vector_type(4)));  // MFMA C/D
typedef float float2v __attribute__((ext_vector_type(2)));  // packed f32 pair

#define NN 2048
#define EPSV 1e-5f
#define EDGEF 2096128.f

__device__ __forceinline__ float bf2f(short s) {
    return __uint_as_float(((unsigned)(unsigned short)s) << 16);
}
__device__ __forceinline__ short f2bf(float f) {   // RNE
    unsigned u = __float_as_uint(f);
    unsigned r = (u + 0x7FFFu + ((u >> 16) & 1u)) >> 16;
    return (short)r;
}
__device__ __forceinline__ float lrelu(float x) { return fmaxf(x, 0.01f * x); }
__device__ __forceinline__ float2v lrelu2(float2v z) {
    float2v r; r.x = fmaxf(z.x, 0.01f * z.x); r.y = fmaxf(z.y, 0.01f * z.y);
    return r;
}
__device__ __forceinline__ float2v fma2(float2v a, float2v b, float2v c) {
    float2v r; r.x = fmaf(a.x, b.x, c.x); r.y = fmaf(a.y, b.y, c.y); return r;
}

// async global->LDS, 16 B per lane. LDS dest is wave-uniform base + lane*16.
__device__ __forceinline__ void gll16(const void* g, void* l) {
    __builtin_amdgcn_global_load_lds(
        (const __attribute__((address_space(1))) void*)g,
        (__attribute__((address_space(3))) void*)l, 16, 0, 0);
}

// fragment-physical chunk index (16x16x32 bf16, A/B identity layout)
__device__ __forceinline__ int physB(int h, int f) {
    return ((((h >> 4) * 2 + (f >> 5)) * 64 + ((f >> 3) & 3) * 16 + (h & 15)) * 8) + (f & 7);
}

// 1-D active-tile decode: rows-of-8 nodes, j-tiles of 64.
// Row ig8 pinned to XCD ig8%8 (blockIdx%8 round-robin heuristic).
// Per-XCD slots: sum_{m=0}^{31}(32-m)=528; grid = 4224.
__device__ __forceinline__ void decode_tile(int bid, int& i0, int& j0, bool& str) {
    int s = bid >> 3, m = 0;
#pragma unroll 1
    while (s >= 32 - m) { s -= 32 - m; ++m; }
    i0 = ((bid & 7) + (m << 3)) * 8;
    j0 = (m + s) * 64;
    str = (s == 0);
}

// ---------------- node layer 1 (+ W5->bf16 conversion on blocks 0..31) -------
__global__ __launch_bounds__(256) void k_l1(const float* __restrict__ nf,
                                            const float* __restrict__ W1,
                                            const float* __restrict__ b1,
                                            const float* __restrict__ W5,
                                            float* __restrict__ act1,
                                            float* __restrict__ stat1,
                                            short* __restrict__ w5bf) {
    __shared__ float xl[8 * 64];
    __shared__ float sS[128], sQ[128];
    int t = threadIdx.x, n0 = blockIdx.x * 8;
    if (blockIdx.x < 32) {                     // fused W5 -> bf16 frag-physical
        int idx = blockIdx.x * 256 + t;        // f*128+h over 8192
        w5bf[physB(idx & 127, idx >> 7)] = f2bf(W5[idx]);
    }
    if (t < 128) { sS[t] = 0.f; sQ[t] = 0.f; }
    xl[t] = nf[(size_t)n0 * 64 + t];
    xl[t + 256] = nf[(size_t)n0 * 64 + t + 256];
    __syncthreads();
    int nl = t >> 5, h0 = (t & 31) * 4;
    float acc[4];
    for (int k = 0; k < 4; ++k) acc[k] = b1[h0 + k];
    for (int f = 0; f < 64; ++f) {
        float r = xl[nl * 64 + f];
        const float* wr = W1 + f * 128 + h0;
        for (int k = 0; k < 4; ++k) acc[k] = fmaf(r, wr[k], acc[k]);
    }
    for (int k = 0; k < 4; ++k) {
        float a = lrelu(acc[k]);
        act1[(size_t)(n0 + nl) * 128 + h0 + k] = a;
        atomicAdd(&sS[h0 + k], a);
        atomicAdd(&sQ[h0 + k], a * a);
    }
    __syncthreads();
    if (t < 128) atomicAdd(&stat1[t], sS[t]);
    else atomicAdd(&stat1[t], sQ[t - 128]);
}

// ---------------- node layer 2 ----------------------------------------------
__global__ __launch_bounds__(256) void k_l2(const float* __restrict__ act1,
                                            const float* __restrict__ stat1,
                                            const float* __restrict__ g1,
                                            const float* __restrict__ be1,
                                            const float* __restrict__ W2,
                                            const float* __restrict__ b2,
                                            float* __restrict__ act2,
                                            float* __restrict__ stat2) {
    __shared__ float a1n[8 * 128];
    __shared__ float sS[128], sQ[128];
    int t = threadIdx.x, n0 = blockIdx.x * 8;
    if (t < 128) { sS[t] = 0.f; sQ[t] = 0.f; }
    for (int k = 0; k < 4; ++k) {
        int e = t + 256 * k;
        int nl = e >> 7, h = e & 127;
        float m = stat1[h] * (1.f / 2048.f);
        float v = stat1[128 + h] * (1.f / 2048.f) - m * m;
        float sc = rsqrtf(v + EPSV);
        a1n[e] = (act1[(size_t)(n0 + nl) * 128 + h] - m) * sc * g1[h] + be1[h];
    }
    __syncthreads();
    int nl = t >> 5, h0 = (t & 31) * 4;
    float acc[4];
    for (int k = 0; k < 4; ++k) acc[k] = b2[h0 + k];
    for (int hi = 0; hi < 128; ++hi) {
        float r = a1n[nl * 128 + hi];
        const float* wr = W2 + hi * 128 + h0;
        for (int k = 0; k < 4; ++k) acc[k] = fmaf(r, wr[k], acc[k]);
    }
    for (int k = 0; k < 4; ++k) {
        float a = lrelu(acc[k]);
        act2[(size_t)(n0 + nl) * 128 + h0 + k] = a;
        atomicAdd(&sS[h0 + k], a);
        atomicAdd(&sQ[h0 + k], a * a);
    }
    __syncthreads();
    if (t < 128) atomicAdd(&stat2[t], sS[t]);
    else atomicAdd(&stat2[t], sQ[t - 128]);
}

// ---------------- node layer 3 + residual -> hb (bf16) + T = diag(h_i)@W5 ---
// Fused k_l3 + k_bi: block b's k_bi part consumed exactly the 8 hb rows
// block b's k_l3 part produces, so keep them in LDS and skip a kernel.
__global__ __launch_bounds__(256) void k_l3bi(const float* __restrict__ act2,
                                              const float* __restrict__ stat2,
                                              const float* __restrict__ g2,
                                              const float* __restrict__ be2,
                                              const float* __restrict__ W3,
                                              const float* __restrict__ b3,
                                              const float* __restrict__ nf,
                                              const short* __restrict__ w5bf,
                                              short* __restrict__ hb,
                                              short* __restrict__ T) {
    __shared__ float a2n[8 * 128];
    __shared__ short sHi[8 * 64];
    int t = threadIdx.x, n0 = blockIdx.x * 8;
    for (int k = 0; k < 4; ++k) {
        int e = t + 256 * k;
        int nl = e >> 7, h = e & 127;
        float m = stat2[h] * (1.f / 2048.f);
        float v = stat2[128 + h] * (1.f / 2048.f) - m * m;
        float sc = rsqrtf(v + EPSV);
        a2n[e] = (act2[(size_t)(n0 + nl) * 128 + h] - m) * sc * g2[h] + be2[h];
    }
    __syncthreads();
    int nl = t >> 5, f0 = (t & 31) * 2;
    float acc[2] = {0.f, 0.f};
    for (int hi = 0; hi < 128; ++hi) {
        float r = a2n[nl * 128 + hi];
        const float* wr = W3 + hi * 64 + f0;
        acc[0] = fmaf(r, wr[0], acc[0]);
        acc[1] = fmaf(r, wr[1], acc[1]);
    }
    float v0 = acc[0] + b3[f0] + nf[(size_t)(n0 + nl) * 64 + f0];
    float v1 = acc[1] + b3[f0 + 1] + nf[(size_t)(n0 + nl) * 64 + f0 + 1];
    unsigned p = (unsigned)(unsigned short)f2bf(v0) |
                 ((unsigned)(unsigned short)f2bf(v1) << 16);
    ((unsigned*)hb)[(size_t)(n0 + nl) * 32 + (f0 >> 1)] = p;
    *(unsigned*)(sHi + nl * 64 + f0) = p;
    __syncthreads();

    // T = diag(h_i) @ W5 (frag-physical), 8 rows of 8192 bf16
    for (int i = 0; i < 8; ++i) {
        short8* dst = (short8*)(T + (size_t)(n0 + i) * 8192);
#pragma unroll
        for (int k = 0; k < 4; ++k) {
            int c = t + 256 * k;                 // chunk 0..1023
            int ks = (c >> 6) & 1, quad = (c & 63) >> 4;
            int fb = ks * 32 + quad * 8;
            short8 wv = ((const short8*)w5bf)[c];
            short8 hv = *(const short8*)(sHi + i * 64 + fb);
            short8 ov;
#pragma unroll
            for (int e = 0; e < 8; ++e) ov[e] = f2bf(bf2f(wv[e]) * bf2f(hv[e]));
            dst[c] = ov;
        }
    }
}

// ---------------- BN+softmax fold (1 block) ----------------------------------
__global__ void k_mid(const float* __restrict__ SQe8, const float* __restrict__ W6,
                      const float* __restrict__ b6, const float* __restrict__ g5,
                      const float* __restrict__ be5, float* __restrict__ w6d,
                      float* __restrict__ b6d) {
    __shared__ float part[128];
    int h = threadIdx.x;
    float s = 0.f, q = 0.f;
    for (int x = 0; x < 8; ++x) {
        s += SQe8[x * 256 + h];
        q += SQe8[x * 256 + 128 + h];
    }
    float m = s / EDGEF;
    float v = q / EDGEF - m * m;
    float sc = rsqrtf(v + EPSV);
    float dW = W6[h * 2] - W6[h * 2 + 1];
    float sg = sc * g5[h];
    w6d[h] = sg * dW;
    part[h] = (be5[h] - m * sg) * dW;
    __syncthreads();
    if (h == 0) {
        float acc = b6[0] - b6[1];
        for (int k = 0; k < 128; ++k) acc += part[k];
        b6d[0] = acc;
    }
}

// ---------------- edge pass 1: BN stats --------------------------------------
// Per-wave async LDS staging of the wave's T-slice (4 KB/i), barrier-free
// double-buffer, counted vmcnt(4) so next-iter loads stay in flight.
__global__ __launch_bounds__(256, 4) void edge_p1(
    const short* __restrict__ hb, const short* __restrict__ T,
    const float* __restrict__ b5, float* __restrict__ SQe8)
{
    __shared__ __align__(16) short lT[2][4][4][512];   // buf, wave, chunk, 64lane*8
    int i0, j0; bool str;
    decode_tile(blockIdx.x, i0, j0, str);

    int t = threadIdx.x, lane = t & 63, w = t >> 6;
    int quad = lane >> 4, col = lane & 15;

    short8 hfr[4][2];
#pragma unroll
    for (int mt = 0; mt < 4; ++mt)
#pragma unroll
        for (int ks = 0; ks < 2; ++ks)
            hfr[mt][ks] = *(const short8*)(hb + (size_t)(j0 + mt * 16 + col) * 64 + ks * 32 + quad * 8);

    // per-lane global source for this wave's slice of T_i: chunk c at +c*512
    const short* Tb = T + (size_t)i0 * 8192 + (size_t)w * 2048 + (size_t)lane * 8;

    float b5c[2] = { b5[w * 32 + col], b5[w * 32 + 16 + col] };
    float2v S2[2], Q2[2];
#pragma unroll
    for (int n = 0; n < 2; ++n) { S2[n] = 0.f; Q2[n] = 0.f; }

    auto stage = [&](int b, int i) {
        const short* Tn = Tb + (size_t)i * 8192;
#pragma unroll
        for (int c = 0; c < 4; ++c)
            gll16(Tn + c * 512, &lT[b][w][c][0]);
    };
    auto ldsread = [&](short8 (&tc)[2][2], int b) {
#pragma unroll
        for (int n = 0; n < 2; ++n)
#pragma unroll
            for (int ks = 0; ks < 2; ++ks)
                tc[n][ks] = *(const short8*)&lT[b][w][n * 2 + ks][lane * 8];
    };

    // clean body: no triangle masking (4160 of 4224 blocks)
    auto bodyC = [&](short8 (&tc)[2][2]) {
#pragma unroll
        for (int n = 0; n < 2; ++n) {
#pragma unroll
            for (int mt = 0; mt < 4; ++mt) {
                floatx4 c = {b5c[n], b5c[n], b5c[n], b5c[n]};
                c = __builtin_amdgcn_mfma_f32_16x16x32_bf16(hfr[mt][0], tc[n][0], c, 0, 0, 0);
                c = __builtin_amdgcn_mfma_f32_16x16x32_bf16(hfr[mt][1], tc[n][1], c, 0, 0, 0);
                float2v z01, z23;
                z01.x = c[0]; z01.y = c[1];
                z23.x = c[2]; z23.y = c[3];
                float2v a01 = lrelu2(z01), a23 = lrelu2(z23);
                S2[n] += a01 + a23;
                Q2[n] = fma2(a01, a01, Q2[n]);
                Q2[n] = fma2(a23, a23, Q2[n]);
            }
        }
    };

    // masked body: diagonal-straddling blocks only (64 of 4224)
    auto bodyM = [&](int i, short8 (&tc)[2][2]) {
        int igi = i0 + i;
#pragma unroll
        for (int n = 0; n < 2; ++n) {
#pragma unroll
            for (int mt = 0; mt < 4; ++mt) {
                floatx4 c = {b5c[n], b5c[n], b5c[n], b5c[n]};
                c = __builtin_amdgcn_mfma_f32_16x16x32_bf16(hfr[mt][0], tc[n][0], c, 0, 0, 0);
                c = __builtin_amdgcn_mfma_f32_16x16x32_bf16(hfr[mt][1], tc[n][1], c, 0, 0, 0);
                int jb = j0 + mt * 16 + quad * 4;
                float2v z01, z23;
                z01.x = (jb + 0 > igi) ? c[0] : 0.f;
                z01.y = (jb + 1 > igi) ? c[1] : 0.f;
                z23.x = (jb + 2 > igi) ? c[2] : 0.f;
                z23.y = (jb + 3 > igi) ? c[3] : 0.f;
                float2v a01 = lrelu2(z01), a23 = lrelu2(z23);
                S2[n] += a01 + a23;
                Q2[n] = fma2(a01, a01, Q2[n]);
                Q2[n] = fma2(a23, a23, Q2[n]);
            }
        }
    };

    stage(0, 0);
    short8 tc[2][2];
    if (!str) {
        for (int i = 0; i < 8; ++i) {
            if (i < 7) {
                stage((i + 1) & 1, i + 1);
                asm volatile("s_waitcnt vmcnt(4)" ::: "memory");
            } else {
                asm volatile("s_waitcnt vmcnt(0)" ::: "memory");
            }
            __builtin_amdgcn_sched_barrier(0);
            ldsread(tc, i & 1);
            bodyC(tc);
        }
    } else {
        for (int i = 0; i < 8; ++i) {
            if (i < 7) {
                stage((i + 1) & 1, i + 1);
                asm volatile("s_waitcnt vmcnt(4)" ::: "memory");
            } else {
                asm volatile("s_waitcnt vmcnt(0)" ::: "memory");
            }
            __builtin_amdgcn_sched_barrier(0);
            ldsread(tc, i & 1);
            bodyM(i, tc);
        }
    }

    float* dst = SQe8 + (blockIdx.x & 7) * 256;
#pragma unroll
    for (int n = 0; n < 2; ++n) {
        float Sa = S2[n].x + S2[n].y;
        float Qa = Q2[n].x + Q2[n].y;
        Sa += __shfl_xor(Sa, 16); Sa += __shfl_xor(Sa, 32);
        Qa += __shfl_xor(Qa, 16); Qa += __shfl_xor(Qa, 32);
        if (quad == 0) {
            atomicAdd(&dst[w * 32 + n * 16 + col], Sa);
            atomicAdd(&dst[128 + w * 32 + n * 16 + col], Qa);
        }
    }
}

// ---------------- edge pass 2: probabilities + symmetric write ---------------
__global__ __launch_bounds__(256, 4) void edge_p2(
    const short* __restrict__ hb, const short* __restrict__ T,
    const float* __restrict__ b5, const float* __restrict__ w6d,
    const float* __restrict__ b6dp, float* __restrict__ out)
{
    __shared__ __align__(16) short lT[2][4][4][512];   // 32 KB staging
    __shared__ float sV[4][8][64];                     // per-wave partial h-sums (8 KB)
    float (*sP)[65] = (float (*)[65])(&lT[0][0][0][0]); // overlays staging after loop

    int i0, j0; bool str;
    decode_tile(blockIdx.x, i0, j0, str);

    int t = threadIdx.x, lane = t & 63, w = t >> 6;
    int quad = lane >> 4, col = lane & 15;

    float bb = b6dp[0];
    float b5q[2][4];
    float2v wq[2][2];                 // w6d at (m, r01/r23)
#pragma unroll
    for (int m = 0; m < 2; ++m)
#pragma unroll
        for (int r = 0; r < 4; ++r) {
            int h = w * 32 + m * 16 + quad * 4 + r;
            b5q[m][r] = b5[h];
            ((float*)&wq[m][r >> 1])[r & 1] = w6d[h];
        }

    short8 hfr[4][2];
#pragma unroll
    for (int mt = 0; mt < 4; ++mt)
#pragma unroll
        for (int ks = 0; ks < 2; ++ks)
            hfr[mt][ks] = *(const short8*)(hb + (size_t)(j0 + mt * 16 + col) * 64 + ks * 32 + quad * 8);

    const short* Tb = T + (size_t)i0 * 8192 + (size_t)w * 2048 + (size_t)lane * 8;

    auto stage = [&](int b, int i) {
        const short* Tn = Tb + (size_t)i * 8192;
#pragma unroll
        for (int c = 0; c < 4; ++c)
            gll16(Tn + c * 512, &lT[b][w][c][0]);
    };
    auto ldsread = [&](short8 (&tc)[2][2], int b) {
#pragma unroll
        for (int m = 0; m < 2; ++m)
#pragma unroll
            for (int ks = 0; ks < 2; ++ks)
                tc[m][ks] = *(const short8*)&lT[b][w][m * 2 + ks][lane * 8];
    };

    auto body2 = [&](int i, short8 (&tc)[2][2]) {
        float2v acc[4];
#pragma unroll
        for (int k = 0; k < 4; ++k) acc[k] = 0.f;
#pragma unroll
        for (int m = 0; m < 2; ++m) {
#pragma unroll
            for (int nj = 0; nj < 4; ++nj) {
                floatx4 c = {b5q[m][0], b5q[m][1], b5q[m][2], b5q[m][3]};
                c = __builtin_amdgcn_mfma_f32_16x16x32_bf16(tc[m][0], hfr[nj][0], c, 0, 0, 0);
                c = __builtin_amdgcn_mfma_f32_16x16x32_bf16(tc[m][1], hfr[nj][1], c, 0, 0, 0);
                float2v z01, z23;
                z01.x = c[0]; z01.y = c[1];
                z23.x = c[2]; z23.y = c[3];
                acc[nj] = fma2(lrelu2(z01), wq[m][0], acc[nj]);
                acc[nj] = fma2(lrelu2(z23), wq[m][1], acc[nj]);
            }
        }
        // per-i tail: quad-butterfly + single-writer plain store (no atomics)
#pragma unroll
        for (int nj = 0; nj < 4; ++nj) {
            float v = acc[nj].x + acc[nj].y;
            v += __shfl_xor(v, 16);
            v += __shfl_xor(v, 32);
            if (quad == 0) sV[w][i][nj * 16 + col] = v;
        }
    };

    stage(0, 0);
    short8 tc[2][2];
    for (int i = 0; i < 8; ++i) {
        if (i < 7) {
            stage((i + 1) & 1, i + 1);
            asm volatile("s_waitcnt vmcnt(4)" ::: "memory");
        } else {
            asm volatile("s_waitcnt vmcnt(0)" ::: "memory");
        }
        __builtin_amdgcn_sched_barrier(0);
        ldsread(tc, i & 1);
        body2(i, tc);
    }
    __syncthreads();   // all waves done with lT -> sP may overlay it

    // cross-wave sum + sigmoid + direct write (coalesced)
#pragma unroll
    for (int k = 0; k < 2; ++k) {
        int e = t + 256 * k;          // 0..511
        int il = e >> 6, jl = e & 63;
        float v = bb + sV[0][il][jl] + sV[1][il][jl] + sV[2][il][jl] + sV[3][il][jl];
        float p = 1.f / (1.f + __expf(-v));
        sP[il][jl] = p;
        int ig = i0 + il, jg = j0 + jl;
        float2v pr;
        if (!str || jg > ig) {
            pr.x = p; pr.y = 1.f - p;
            *(float2v*)(out + ((size_t)ig * NN + jg) * 2) = pr;
        } else if (jg == ig) {
            pr.x = 0.f; pr.y = 0.f;
            *(float2v*)(out + ((size_t)ig * NN + jg) * 2) = pr;
        }
    }
    __syncthreads();

    if (!str) {
        // mirror: 64 rows x 16 floats, float4 per thread
        int jr = t >> 2, f1 = (t & 3) * 4;
        float4 u;
#pragma unroll
        for (int e = 0; e < 4; ++e) {
            int ff = f1 + e;
            float p = sP[ff >> 1][jr];
            ((float*)&u)[e] = (ff & 1) ? 1.f - p : p;
        }
        *(float4*)(out + ((size_t)(j0 + jr) * NN + i0) * 2 + f1) = u;
    } else {
#pragma unroll
        for (int e = 0; e < 4; ++e) {     // mirror 64x8x2 = 1024 floats
            int f = t * 4 + e;
            int jr = f >> 4, ff = f & 15;
            int il = ff >> 1, c2 = ff & 1;
            int jg = j0 + jr, ig = i0 + il;
            if (jg > ig) {
                float p = sP[il][jr];
                out[((size_t)jg * NN + ig) * 2 + c2] = c2 ? 1.f - p : p;
            }
        }
    }
}

// ---------------------------------------------------------------------------
extern "C" void kernel_launch(void* const* d_in, const int* in_sizes, int n_in,
                              void* d_out, int out_size, void* d_ws, size_t ws_size,
                              hipStream_t stream) {
    const float* nf  = (const float*)d_in[1];   // d_in[0]=x unused (ref ignores it)
    const float* W1  = (const float*)d_in[2];
    const float* b1  = (const float*)d_in[3];
    const float* g1  = (const float*)d_in[4];
    const float* be1 = (const float*)d_in[5];
    const float* W2  = (const float*)d_in[6];
    const float* b2  = (const float*)d_in[7];
    const float* g2  = (const float*)d_in[8];
    const float* be2 = (const float*)d_in[9];
    const float* W3  = (const float*)d_in[10];
    const float* b3  = (const float*)d_in[11];
    const float* W5  = (const float*)d_in[12];
    const float* b5  = (const float*)d_in[13];
    const float* g5  = (const float*)d_in[14];
    const float* be5 = (const float*)d_in[15];
    const float* W6  = (const float*)d_in[16];
    const float* b6  = (const float*)d_in[17];
    float* out = (float*)d_out;

    float* wsf   = (float*)d_ws;
    float* stat1 = wsf;                 // 256
    float* stat2 = wsf + 256;           // 256
    float* SQe8  = wsf + 512;           // 8*256 = 2048 (per-XCD stat copies)
    float* w6d   = wsf + 2560;          // 128
    float* b6dp  = wsf + 2688;          // 1 (pad to 4096)
    float* act1  = wsf + 4096;          // 262144
    float* act2  = act1 + 262144;       // 262144
    short* hb    = (short*)(act2 + 262144);   // 131072 bf16
    short* w5bf  = hb + 131072;               // 8192 bf16
    short* Tbuf  = w5bf + 8192;               // 2048*8192 bf16 = 32 MB

    hipMemsetAsync(d_ws, 0, 4096 * sizeof(float), stream);

    k_l1<<<256, 256, 0, stream>>>(nf, W1, b1, W5, act1, stat1, w5bf);
    k_l2<<<256, 256, 0, stream>>>(act1, stat1, g1, be1, W2, b2, act2, stat2);
    k_l3bi<<<256, 256, 0, stream>>>(act2, stat2, g2, be2, W3, b3, nf, w5bf, hb, Tbuf);

    edge_p1<<<4224, 256, 0, stream>>>(hb, Tbuf, b5, SQe8);
    k_mid<<<1, 128, 0, stream>>>(SQe8, W6, b6, g5, be5, w6d, b6dp);
    edge_p2<<<4224, 256, 0, stream>>>(hb, Tbuf, b5, w6d, b6dp, out);
}

// Round 3
// 251.896 us; speedup vs baseline: 1.1450x; 1.1450x over previous
//
#include <hip/hip_runtime.h>
#include <hip/hip_bf16.h>

// ---------------------------------------------------------------------------
// ramsey_NN: node MLP (3 layers, train-mode BN) + all-pairs edge head.
// N=2048, F=64, H=128, C=2.  E = N(N-1)/2 = 2096128.
//
// R11 vs R10 (R10 regressed: LDS staging added a serial vmcnt->lgkm->MFMA
// chain; real bottleneck = 528 MB of T re-reads, latency-bound at ~31%
// per-SIMD issue):
//   * T (32 MB) ELIMINATED. Edge pass tiles PAIRS (16 i x 64 j per block,
//     2112 blocks). A-frag = bf16(h_i[f]*h_j[f]) formed in-register:
//     h_j frag = old hfr layout from hb; h_i = broadcast ds_read from an
//     8 KB LDS f32 copy; product packed via v_cvt_pk_bf16_f32.
//     B = W5 frags (w5bf frag-physical chunks (n*2+ks)*64+lane) entirely
//     in registers, loaded once per block. Traffic 528 MB -> ~20 MB.
//   * k_l3 back to plain (no T gen, no k_bi); also stores f32 h (hf).
//   * epilogues: p1 scalar S/Q per h-chunk + quad-shfl reduce + atomics
//     (unchanged scheme); p2 in-register h-dot with w6d + 16-lane shfl
//     reduce + sigmoid + sP LDS + coalesced symmetric write.
// ---------------------------------------------------------------------------

typedef short short8 __attribute__((ext_vector_type(8)));   // 8 x bf16
typedef float floatx4 __attribute__((ext_vector_type(4)));  // MFMA C/D
typedef float float2v __attribute__((ext_vector_type(2)));  // packed f32 pair

#define NN 2048
#define EPSV 1e-5f
#define EDGEF 2096128.f

__device__ __forceinline__ float bf2f(short s) {
    return __uint_as_float(((unsigned)(unsigned short)s) << 16);
}
__device__ __forceinline__ short f2bf(float f) {   // RNE
    unsigned u = __float_as_uint(f);
    unsigned r = (u + 0x7FFFu + ((u >> 16) & 1u)) >> 16;
    return (short)r;
}
__device__ __forceinline__ float lrelu(float x) { return fmaxf(x, 0.01f * x); }

// pack two f32 -> one u32 of 2 bf16 (lo = a, hi = b)
__device__ __forceinline__ unsigned cvt_pk_bf16(float a, float b) {
    unsigned r;
    asm("v_cvt_pk_bf16_f32 %0, %1, %2" : "=v"(r) : "v"(a), "v"(b));
    return r;
}

// fragment-physical chunk index (16x16x32 bf16, A/B identity layout)
__device__ __forceinline__ int physB(int h, int f) {
    return ((((h >> 4) * 2 + (f >> 5)) * 64 + ((f >> 3) & 3) * 16 + (h & 15)) * 8) + (f & 7);
}

// pair-tile decode: i-groups of 16, j-tiles of 64, upper triangle.
// For i-group g (0..127), j-tiles run from q=(g>>2) to 31 -> count 32-q.
// cum(q) = 130q - 2q^2 blocks before quad-group q. Grid = 2112.
__device__ __forceinline__ void decode2(int bid, int& i0, int& j0, bool& str) {
    int q = (int)(0.25f * (130.f - sqrtf(16900.f - 8.f * (float)bid)));
    if (q < 0) q = 0;
    while (q > 0 && 130 * q - 2 * q * q > bid) --q;
    while (130 * (q + 1) - 2 * (q + 1) * (q + 1) <= bid) ++q;
    int r = bid - (130 * q - 2 * q * q);
    int n = 32 - q;
    int gs = (r >= n) + (r >= 2 * n) + (r >= 3 * n);
    int g = 4 * q + gs;
    int s = r - gs * n;
    i0 = g * 16;
    j0 = (q + s) * 64;
    str = (s == 0);
}

// ---------------- node layer 1 (+ W5->bf16 conversion on blocks 0..31) -------
__global__ __launch_bounds__(256) void k_l1(const float* __restrict__ nf,
                                            const float* __restrict__ W1,
                                            const float* __restrict__ b1,
                                            const float* __restrict__ W5,
                                            float* __restrict__ act1,
                                            float* __restrict__ stat1,
                                            short* __restrict__ w5bf) {
    __shared__ float xl[8 * 64];
    __shared__ float sS[128], sQ[128];
    int t = threadIdx.x, n0 = blockIdx.x * 8;
    if (blockIdx.x < 32) {                     // fused W5 -> bf16 frag-physical
        int idx = blockIdx.x * 256 + t;        // f*128+h over 8192
        w5bf[physB(idx & 127, idx >> 7)] = f2bf(W5[idx]);
    }
    if (t < 128) { sS[t] = 0.f; sQ[t] = 0.f; }
    xl[t] = nf[(size_t)n0 * 64 + t];
    xl[t + 256] = nf[(size_t)n0 * 64 + t + 256];
    __syncthreads();
    int nl = t >> 5, h0 = (t & 31) * 4;
    float acc[4];
    for (int k = 0; k < 4; ++k) acc[k] = b1[h0 + k];
    for (int f = 0; f < 64; ++f) {
        float r = xl[nl * 64 + f];
        const float* wr = W1 + f * 128 + h0;
        for (int k = 0; k < 4; ++k) acc[k] = fmaf(r, wr[k], acc[k]);
    }
    for (int k = 0; k < 4; ++k) {
        float a = lrelu(acc[k]);
        act1[(size_t)(n0 + nl) * 128 + h0 + k] = a;
        atomicAdd(&sS[h0 + k], a);
        atomicAdd(&sQ[h0 + k], a * a);
    }
    __syncthreads();
    if (t < 128) atomicAdd(&stat1[t], sS[t]);
    else atomicAdd(&stat1[t], sQ[t - 128]);
}

// ---------------- node layer 2 ----------------------------------------------
__global__ __launch_bounds__(256) void k_l2(const float* __restrict__ act1,
                                            const float* __restrict__ stat1,
                                            const float* __restrict__ g1,
                                            const float* __restrict__ be1,
                                            const float* __restrict__ W2,
                                            const float* __restrict__ b2,
                                            float* __restrict__ act2,
                                            float* __restrict__ stat2) {
    __shared__ float a1n[8 * 128];
    __shared__ float sS[128], sQ[128];
    int t = threadIdx.x, n0 = blockIdx.x * 8;
    if (t < 128) { sS[t] = 0.f; sQ[t] = 0.f; }
    for (int k = 0; k < 4; ++k) {
        int e = t + 256 * k;
        int nl = e >> 7, h = e & 127;
        float m = stat1[h] * (1.f / 2048.f);
        float v = stat1[128 + h] * (1.f / 2048.f) - m * m;
        float sc = rsqrtf(v + EPSV);
        a1n[e] = (act1[(size_t)(n0 + nl) * 128 + h] - m) * sc * g1[h] + be1[h];
    }
    __syncthreads();
    int nl = t >> 5, h0 = (t & 31) * 4;
    float acc[4];
    for (int k = 0; k < 4; ++k) acc[k] = b2[h0 + k];
    for (int hi = 0; hi < 128; ++hi) {
        float r = a1n[nl * 128 + hi];
        const float* wr = W2 + hi * 128 + h0;
        for (int k = 0; k < 4; ++k) acc[k] = fmaf(r, wr[k], acc[k]);
    }
    for (int k = 0; k < 4; ++k) {
        float a = lrelu(acc[k]);
        act2[(size_t)(n0 + nl) * 128 + h0 + k] = a;
        atomicAdd(&sS[h0 + k], a);
        atomicAdd(&sQ[h0 + k], a * a);
    }
    __syncthreads();
    if (t < 128) atomicAdd(&stat2[t], sS[t]);
    else atomicAdd(&stat2[t], sQ[t - 128]);
}

// ---------------- node layer 3 + residual -> hb (bf16) + hf (f32) -----------
__global__ __launch_bounds__(256) void k_l3(const float* __restrict__ act2,
                                            const float* __restrict__ stat2,
                                            const float* __restrict__ g2,
                                            const float* __restrict__ be2,
                                            const float* __restrict__ W3,
                                            const float* __restrict__ b3,
                                            const float* __restrict__ nf,
                                            short* __restrict__ hb,
                                            float* __restrict__ hf) {
    __shared__ float a2n[8 * 128];
    int t = threadIdx.x, n0 = blockIdx.x * 8;
    for (int k = 0; k < 4; ++k) {
        int e = t + 256 * k;
        int nl = e >> 7, h = e & 127;
        float m = stat2[h] * (1.f / 2048.f);
        float v = stat2[128 + h] * (1.f / 2048.f) - m * m;
        float sc = rsqrtf(v + EPSV);
        a2n[e] = (act2[(size_t)(n0 + nl) * 128 + h] - m) * sc * g2[h] + be2[h];
    }
    __syncthreads();
    int nl = t >> 5, f0 = (t & 31) * 2;
    float acc[2] = {0.f, 0.f};
    for (int hi = 0; hi < 128; ++hi) {
        float r = a2n[nl * 128 + hi];
        const float* wr = W3 + hi * 64 + f0;
        acc[0] = fmaf(r, wr[0], acc[0]);
        acc[1] = fmaf(r, wr[1], acc[1]);
    }
    float v0 = acc[0] + b3[f0] + nf[(size_t)(n0 + nl) * 64 + f0];
    float v1 = acc[1] + b3[f0 + 1] + nf[(size_t)(n0 + nl) * 64 + f0 + 1];
    unsigned p = (unsigned)(unsigned short)f2bf(v0) |
                 ((unsigned)(unsigned short)f2bf(v1) << 16);
    ((unsigned*)hb)[(size_t)(n0 + nl) * 32 + (f0 >> 1)] = p;
    hf[(size_t)(n0 + nl) * 64 + f0] = v0;
    hf[(size_t)(n0 + nl) * 64 + f0 + 1] = v1;
}

// ---------------- BN+softmax fold (1 block) ----------------------------------
__global__ void k_mid(const float* __restrict__ SQe8, const float* __restrict__ W6,
                      const float* __restrict__ b6, const float* __restrict__ g5,
                      const float* __restrict__ be5, float* __restrict__ w6d,
                      float* __restrict__ b6d) {
    __shared__ float part[128];
    int h = threadIdx.x;
    float s = 0.f, q = 0.f;
    for (int x = 0; x < 8; ++x) {
        s += SQe8[x * 256 + h];
        q += SQe8[x * 256 + 128 + h];
    }
    float m = s / EDGEF;
    float v = q / EDGEF - m * m;
    float sc = rsqrtf(v + EPSV);
    float dW = W6[h * 2] - W6[h * 2 + 1];
    float sg = sc * g5[h];
    w6d[h] = sg * dW;
    part[h] = (be5[h] - m * sg) * dW;
    __syncthreads();
    if (h == 0) {
        float acc = b6[0] - b6[1];
        for (int k = 0; k < 128; ++k) acc += part[k];
        b6d[0] = acc;
    }
}

// ---------------- edge pass 1: BN stats (pair-tile, T-free) ------------------
__global__ __launch_bounds__(256, 3) void edge_p1(
    const short* __restrict__ hb, const float* __restrict__ hf,
    const short* __restrict__ w5bf, const float* __restrict__ b5,
    float* __restrict__ SQe8)
{
    __shared__ __align__(16) float hi[16 * 64];   // 4 KB, f32 h_i rows
    int i0, j0; bool str;
    decode2(blockIdx.x, i0, j0, str);
    int t = threadIdx.x, lane = t & 63, w = t >> 6;
    int quad = lane >> 4, col = lane & 15;

    // stage h_i (16 rows x 64 f32) -- one float4 per thread
    ((float4*)hi)[t] = ((const float4*)(hf + (size_t)i0 * 64))[t];

    // h_j fragment (wave's 16 rows), unpacked to f32 (= bf16<<16, exact)
    float hjf[2][8];
#pragma unroll
    for (int ks = 0; ks < 2; ++ks) {
        short8 hv = *(const short8*)(hb + (size_t)(j0 + w * 16 + col) * 64 + ks * 32 + quad * 8);
#pragma unroll
        for (int e = 0; e < 8; ++e) hjf[ks][e] = bf2f(hv[e]);
    }
    // W5 fragments: all 128 h, in registers (64 VGPR)
    short8 w5f[8][2];
#pragma unroll
    for (int n = 0; n < 8; ++n)
#pragma unroll
        for (int ks = 0; ks < 2; ++ks)
            w5f[n][ks] = ((const short8*)w5bf)[(n * 2 + ks) * 64 + lane];
    float b5v[8];
#pragma unroll
    for (int n = 0; n < 8; ++n) b5v[n] = b5[n * 16 + col];

    float S[8], Q[8];
#pragma unroll
    for (int n = 0; n < 8; ++n) { S[n] = 0.f; Q[n] = 0.f; }
    floatx4 zero4 = {0.f, 0.f, 0.f, 0.f};

    __syncthreads();

    auto mkfrag = [&](int il, short8 (&af)[2]) {
#pragma unroll
        for (int ks = 0; ks < 2; ++ks) {
            const float* hp = &hi[il * 64 + ks * 32 + quad * 8];
            float4 h0 = *(const float4*)hp;
            float4 h1 = *(const float4*)(hp + 4);
            int4 aw;
            aw.x = cvt_pk_bf16(h0.x * hjf[ks][0], h0.y * hjf[ks][1]);
            aw.y = cvt_pk_bf16(h0.z * hjf[ks][2], h0.w * hjf[ks][3]);
            aw.z = cvt_pk_bf16(h1.x * hjf[ks][4], h1.y * hjf[ks][5]);
            aw.w = cvt_pk_bf16(h1.z * hjf[ks][6], h1.w * hjf[ks][7]);
            af[ks] = *(short8*)&aw;
        }
    };

    if (!str) {
#pragma unroll 2
        for (int il = 0; il < 16; ++il) {
            short8 af[2];
            mkfrag(il, af);
#pragma unroll
            for (int n = 0; n < 8; ++n) {
                floatx4 c = __builtin_amdgcn_mfma_f32_16x16x32_bf16(af[0], w5f[n][0], zero4, 0, 0, 0);
                c = __builtin_amdgcn_mfma_f32_16x16x32_bf16(af[1], w5f[n][1], c, 0, 0, 0);
                float b = b5v[n];
#pragma unroll
                for (int r = 0; r < 4; ++r) {
                    float a = lrelu(c[r] + b);
                    S[n] += a;
                    Q[n] = fmaf(a, a, Q[n]);
                }
            }
        }
    } else {
        int jgb = j0 + w * 16 + quad * 4;
#pragma unroll 2
        for (int il = 0; il < 16; ++il) {
            short8 af[2];
            mkfrag(il, af);
            int ig = i0 + il;
#pragma unroll
            for (int n = 0; n < 8; ++n) {
                floatx4 c = __builtin_amdgcn_mfma_f32_16x16x32_bf16(af[0], w5f[n][0], zero4, 0, 0, 0);
                c = __builtin_amdgcn_mfma_f32_16x16x32_bf16(af[1], w5f[n][1], c, 0, 0, 0);
                float b = b5v[n];
#pragma unroll
                for (int r = 0; r < 4; ++r) {
                    float a = (jgb + r > ig) ? lrelu(c[r] + b) : 0.f;
                    S[n] += a;
                    Q[n] = fmaf(a, a, Q[n]);
                }
            }
        }
    }

    float* dst = SQe8 + (blockIdx.x & 7) * 256;
#pragma unroll
    for (int n = 0; n < 8; ++n) {
        float Sa = S[n], Qa = Q[n];
        Sa += __shfl_xor(Sa, 16); Sa += __shfl_xor(Sa, 32);
        Qa += __shfl_xor(Qa, 16); Qa += __shfl_xor(Qa, 32);
        if (quad == 0) {
            atomicAdd(&dst[n * 16 + col], Sa);
            atomicAdd(&dst[128 + n * 16 + col], Qa);
        }
    }
}

// ---------------- edge pass 2: probabilities + symmetric write ---------------
__global__ __launch_bounds__(256, 3) void edge_p2(
    const short* __restrict__ hb, const float* __restrict__ hf,
    const short* __restrict__ w5bf, const float* __restrict__ b5,
    const float* __restrict__ w6d, const float* __restrict__ b6dp,
    float* __restrict__ out)
{
    __shared__ __align__(16) float hi[16 * 64];   // 4 KB
    __shared__ float sp[16][65];                  // probs, padded
    int i0, j0; bool str;
    decode2(blockIdx.x, i0, j0, str);
    int t = threadIdx.x, lane = t & 63, w = t >> 6;
    int quad = lane >> 4, col = lane & 15;

    ((float4*)hi)[t] = ((const float4*)(hf + (size_t)i0 * 64))[t];

    float hjf[2][8];
#pragma unroll
    for (int ks = 0; ks < 2; ++ks) {
        short8 hv = *(const short8*)(hb + (size_t)(j0 + w * 16 + col) * 64 + ks * 32 + quad * 8);
#pragma unroll
        for (int e = 0; e < 8; ++e) hjf[ks][e] = bf2f(hv[e]);
    }
    short8 w5f[8][2];
#pragma unroll
    for (int n = 0; n < 8; ++n)
#pragma unroll
        for (int ks = 0; ks < 2; ++ks)
            w5f[n][ks] = ((const short8*)w5bf)[(n * 2 + ks) * 64 + lane];
    float b5v[8], w6v[8];
#pragma unroll
    for (int n = 0; n < 8; ++n) {
        b5v[n] = b5[n * 16 + col];
        w6v[n] = w6d[n * 16 + col];
    }
    float bb = b6dp[0];
    floatx4 zero4 = {0.f, 0.f, 0.f, 0.f};

    __syncthreads();

    auto mkfrag = [&](int il, short8 (&af)[2]) {
#pragma unroll
        for (int ks = 0; ks < 2; ++ks) {
            const float* hp = &hi[il * 64 + ks * 32 + quad * 8];
            float4 h0 = *(const float4*)hp;
            float4 h1 = *(const float4*)(hp + 4);
            int4 aw;
            aw.x = cvt_pk_bf16(h0.x * hjf[ks][0], h0.y * hjf[ks][1]);
            aw.y = cvt_pk_bf16(h0.z * hjf[ks][2], h0.w * hjf[ks][3]);
            aw.z = cvt_pk_bf16(h1.x * hjf[ks][4], h1.y * hjf[ks][5]);
            aw.w = cvt_pk_bf16(h1.z * hjf[ks][6], h1.w * hjf[ks][7]);
            af[ks] = *(short8*)&aw;
        }
    };

#pragma unroll 2
    for (int il = 0; il < 16; ++il) {
        short8 af[2];
        mkfrag(il, af);
        float acc[4] = {0.f, 0.f, 0.f, 0.f};
#pragma unroll
        for (int n = 0; n < 8; ++n) {
            floatx4 c = __builtin_amdgcn_mfma_f32_16x16x32_bf16(af[0], w5f[n][0], zero4, 0, 0, 0);
            c = __builtin_amdgcn_mfma_f32_16x16x32_bf16(af[1], w5f[n][1], c, 0, 0, 0);
            float b = b5v[n], wv = w6v[n];
#pragma unroll
            for (int r = 0; r < 4; ++r)
                acc[r] = fmaf(lrelu(c[r] + b), wv, acc[r]);
        }
        // reduce over the 16 h-cols (lane bits 0..3)
#pragma unroll
        for (int d = 1; d < 16; d <<= 1)
#pragma unroll
            for (int r = 0; r < 4; ++r) acc[r] += __shfl_xor(acc[r], d);
        if (col == 0) {
#pragma unroll
            for (int r = 0; r < 4; ++r) {
                float v = acc[r] + bb;
                sp[il][w * 16 + quad * 4 + r] = 1.f / (1.f + __expf(-v));
            }
        }
    }
    __syncthreads();

    if (!str) {
        // forward: 16 rows x 64 pairs x 2 floats (coalesced float4)
        int il = t >> 4, jb = (t & 15) * 4;
        float* op = out + ((size_t)(i0 + il) * NN + j0 + jb) * 2;
#pragma unroll
        for (int q2 = 0; q2 < 2; ++q2) {
            float p0 = sp[il][jb + q2 * 2], p1 = sp[il][jb + q2 * 2 + 1];
            float4 u; u.x = p0; u.y = 1.f - p0; u.z = p1; u.w = 1.f - p1;
            *(float4*)(op + q2 * 4) = u;
        }
        // mirror: 64 rows x 16 x 2
        int jl = t >> 2, ib = (t & 3) * 4;
        float* om = out + ((size_t)(j0 + jl) * NN + i0 + ib) * 2;
#pragma unroll
        for (int q2 = 0; q2 < 2; ++q2) {
            float p0 = sp[ib + q2 * 2][jl], p1 = sp[ib + q2 * 2 + 1][jl];
            float4 u; u.x = p0; u.y = 1.f - p0; u.z = p1; u.w = 1.f - p1;
            *(float4*)(om + q2 * 4) = u;
        }
    } else {
        int il = t >> 4, jb = (t & 15) * 4;
        int ig = i0 + il;
#pragma unroll
        for (int e = 0; e < 4; ++e) {
            int jg = j0 + jb + e;
            if (jg > ig) {
                float p = sp[il][jb + e];
                float2v pr; pr.x = p; pr.y = 1.f - p;
                *(float2v*)(out + ((size_t)ig * NN + jg) * 2) = pr;
            } else if (jg == ig) {
                float2v pr; pr.x = 0.f; pr.y = 0.f;
                *(float2v*)(out + ((size_t)ig * NN + jg) * 2) = pr;
            }
        }
        int jl = t >> 2, ib = (t & 3) * 4;
        int jg = j0 + jl;
#pragma unroll
        for (int e = 0; e < 4; ++e) {
            int ig2 = i0 + ib + e;
            if (jg > ig2) {
                float p = sp[ib + e][jl];
                float2v pr; pr.x = p; pr.y = 1.f - p;
                *(float2v*)(out + ((size_t)jg * NN + ig2) * 2) = pr;
            }
        }
    }
}

// ---------------------------------------------------------------------------
extern "C" void kernel_launch(void* const* d_in, const int* in_sizes, int n_in,
                              void* d_out, int out_size, void* d_ws, size_t ws_size,
                              hipStream_t stream) {
    const float* nf  = (const float*)d_in[1];   // d_in[0]=x unused (ref ignores it)
    const float* W1  = (const float*)d_in[2];
    const float* b1  = (const float*)d_in[3];
    const float* g1  = (const float*)d_in[4];
    const float* be1 = (const float*)d_in[5];
    const float* W2  = (const float*)d_in[6];
    const float* b2  = (const float*)d_in[7];
    const float* g2  = (const float*)d_in[8];
    const float* be2 = (const float*)d_in[9];
    const float* W3  = (const float*)d_in[10];
    const float* b3  = (const float*)d_in[11];
    const float* W5  = (const float*)d_in[12];
    const float* b5  = (const float*)d_in[13];
    const float* g5  = (const float*)d_in[14];
    const float* be5 = (const float*)d_in[15];
    const float* W6  = (const float*)d_in[16];
    const float* b6  = (const float*)d_in[17];
    float* out = (float*)d_out;

    float* wsf   = (float*)d_ws;
    float* stat1 = wsf;                 // 256
    float* stat2 = wsf + 256;           // 256
    float* SQe8  = wsf + 512;           // 8*256 = 2048 (8 spread copies)
    float* w6d   = wsf + 2560;          // 128
    float* b6dp  = wsf + 2688;          // 1 (pad to 4096)
    float* act1  = wsf + 4096;          // 262144
    float* act2  = act1 + 262144;       // 262144
    short* hb    = (short*)(act2 + 262144);   // 131072 bf16
    short* w5bf  = hb + 131072;               // 8192 bf16
    float* hf    = (float*)(w5bf + 8192);     // 131072 f32

    hipMemsetAsync(d_ws, 0, 4096 * sizeof(float), stream);

    k_l1<<<256, 256, 0, stream>>>(nf, W1, b1, W5, act1, stat1, w5bf);
    k_l2<<<256, 256, 0, stream>>>(act1, stat1, g1, be1, W2, b2, act2, stat2);
    k_l3<<<256, 256, 0, stream>>>(act2, stat2, g2, be2, W3, b3, nf, hb, hf);

    edge_p1<<<2112, 256, 0, stream>>>(hb, hf, w5bf, b5, SQe8);
    k_mid<<<1, 128, 0, stream>>>(SQe8, W6, b6, g5, be5, w6d, b6dp);
    edge_p2<<<2112, 256, 0, stream>>>(hb, hf, w5bf, b5, w6d, b6dp, out);
}